// Round 6
// baseline (2091.385 us; speedup 1.0000x reference)
//
#include <hip/hip_runtime.h>

// Problem constants (fixed by the reference)
#define BD 8
#define SD 4096
#define DDIM 512
#define QD 8
#define CDN 1024
#define ROWS (BD * SD)              // 32768
#define QUANT_ELEMS (ROWS * DDIM)   // 16777216
#define IDX_OFF QUANT_ELEMS
#define LOSS_OFF (QUANT_ELEMS + ROWS * QD)

#define TPB 256
#define BR 32                       // rows per block
#define CT 256                      // codes per ct-iter
#define NCT 4
#define NKC 16                      // K chunks of 32
#define ASTR 40                     // LDS A stride in ushorts (80 B, 16B-aligned)
// 3-MFMA split (ah*bh + ah*bl + al*bh): max dist error ~2e-3 << MARGIN/2.
#define MARGIN 0.25f

// ws layout (bytes)
#define WS_LOSS 0                   // 8 doubles
#define WS_FBCNT 64                 // 8 ints
#define WS_FBLIST 4096              // 32768 ints (128 KB)
#define WS_NORMS 0x40000            // 32 KB
#define WS_PKHI 0x100000            // 8 MB (all levels)
#define WS_PKLO 0x900000            // 8 MB
#define WS_RESID 0x1100000          // 64 MB

typedef __attribute__((ext_vector_type(8))) short short8;
typedef __attribute__((ext_vector_type(4))) float f32x4;

__device__ __forceinline__ ushort f2bf(float x) {
    unsigned u = __float_as_uint(x);
    u += 0x7fff + ((u >> 16) & 1);          // RTNE
    return (ushort)(u >> 16);
}

// ---------------------------------------------------------------- norms
__global__ __launch_bounds__(256) void vq_norms(const float* __restrict__ cb,
                                                float* __restrict__ norms) {
    int code = blockIdx.x * 4 + (threadIdx.x >> 6);
    int lane = threadIdx.x & 63;
    const float4* p = (const float4*)(cb + (size_t)code * DDIM);
    float4 a = p[lane];
    float4 b = p[lane + 64];
    float s = a.x * a.x + a.y * a.y + a.z * a.z + a.w * a.w +
              b.x * b.x + b.y * b.y + b.z * b.z + b.w * b.w;
#pragma unroll
    for (int m = 32; m >= 1; m >>= 1) s += __shfl_xor(s, m);
    if (lane == 0) norms[code] = s;
}

// ---------------------------------------------------------------- cb pack (ALL levels)
// Frag-major bf16 hi/lo per level: slot s covers code=tile*16+(lane&15),
// k = kc*32 + (lane>>4)*8 + j.  Wave B-load = 64 lanes x 16B contiguous.
__global__ __launch_bounds__(256) void vq_cbpack(const float* __restrict__ cbs,
                                                 ushort* __restrict__ pkHi,
                                                 ushort* __restrict__ pkLo) {
    int sg = blockIdx.x * 256 + threadIdx.x;   // 0..524287 (8 levels x 65536 slots)
    int lvl = sg >> 16;
    int s = sg & 65535;
    int tile = s >> 10;
    int kc = (s >> 6) & 15;
    int ln = s & 63;
    int code = tile * 16 + (ln & 15);
    int k0 = kc * 32 + (ln >> 4) * 8;
    const float* p = cbs + (size_t)lvl * CDN * DDIM + (size_t)code * DDIM + k0;
    float f[8];
    *(float4*)&f[0] = *(const float4*)p;
    *(float4*)&f[4] = *(const float4*)(p + 4);
    ushort h[8], l[8];
#pragma unroll
    for (int i = 0; i < 8; i++) {
        h[i] = f2bf(f[i]);
        float hf = __uint_as_float(((unsigned)h[i]) << 16);
        l[i] = f2bf(f[i] - hf);
    }
    *(short8*)(pkHi + (size_t)sg * 8) = *(short8*)h;
    *(short8*)(pkLo + (size_t)sg * 8) = *(short8*)l;
}

// ---------------------------------------------------------------- fused level (MFMA)
// 4 waves = 4 code-groups (cg), each wave covers all 32 rows x 64 codes per
// ct-iter; no B redundancy within a block. grid=1024 -> ~4 blocks/CU.
__global__ __launch_bounds__(TPB, 2) void vq_level_mfma(
    const float* __restrict__ rsrc, const float* __restrict__ qsub,
    float* __restrict__ resid, float* __restrict__ quant,
    const float* __restrict__ cbq, const float* __restrict__ normq,
    const ushort* __restrict__ pkHi, const ushort* __restrict__ pkLo,
    float* __restrict__ idx_out, double* __restrict__ lossq,
    int* __restrict__ fbCnt, int* __restrict__ fbList, int q) {
    __shared__ ushort Ah[2][BR][ASTR];       // 5120 B
    __shared__ ushort Al[2][BR][ASTR];       // 5120 B
    __shared__ float s_nrm[CDN];             // 4 KB
    __shared__ float m_d1[4][BR], m_d2[4][BR], m_d3[4][BR];
    __shared__ int m_i1[4][BR], m_i2[4][BR];
    __shared__ int s_i1[BR], s_i2[BR], s_flag[BR];
    __shared__ double s_part[4];

    int tid = threadIdx.x;
    int lane = tid & 63;
    int l15 = lane & 15;
    int quad = lane >> 4;
    int cg = tid >> 6;      // wave = code group (0..3)
    int row0 = blockIdx.x * BR;

    for (int i = tid; i < CDN; i += TPB) s_nrm[i] = normq[i];

    // per-lane top-3 per slot (rt*4+reg)
    float td1[8], td2[8], td3[8];
    int ti1[8], ti2[8];
#pragma unroll
    for (int s = 0; s < 8; s++) { td1[s] = 3.4e38f; td2[s] = 3.4e38f; td3[s] = 3.4e38f; ti1[s] = 0; ti2[s] = 0; }

    // staging: 32 rows x 32 dims per kc; 256 threads x 4 floats
    int st_row = tid >> 3;          // 0..31
    int st_k4 = (tid & 7) * 4;      // 0..28
    size_t st_base = (size_t)(row0 + st_row) * DDIM + st_k4;

    for (int ct = 0; ct < NCT; ct++) {
        f32x4 acc[2][4];
#pragma unroll
        for (int rt = 0; rt < 2; rt++)
#pragma unroll
            for (int j = 0; j < 4; j++) acc[rt][j] = (f32x4)0.0f;

        __syncthreads();
        {   // stage kc=0 into buf 0
            float4 v = *(const float4*)(rsrc + st_base);
            if (qsub) {
                float4 w = *(const float4*)(qsub + st_base);
                v.x -= w.x; v.y -= w.y; v.z -= w.z; v.w -= w.w;
            }
            ushort4 h, l;
            h.x = f2bf(v.x); l.x = f2bf(v.x - __uint_as_float(((unsigned)h.x) << 16));
            h.y = f2bf(v.y); l.y = f2bf(v.y - __uint_as_float(((unsigned)h.y) << 16));
            h.z = f2bf(v.z); l.z = f2bf(v.z - __uint_as_float(((unsigned)h.z) << 16));
            h.w = f2bf(v.w); l.w = f2bf(v.w - __uint_as_float(((unsigned)h.w) << 16));
            *(ushort4*)&Ah[0][st_row][st_k4] = h;
            *(ushort4*)&Al[0][st_row][st_k4] = l;
        }
        __syncthreads();

        for (int kc = 0; kc < NKC; kc++) {
            int buf = kc & 1;
            float4 v;
            bool pref = (kc < NKC - 1);
            if (pref) {
                size_t g = st_base + (size_t)(kc + 1) * 32;
                v = *(const float4*)(rsrc + g);
                if (qsub) {
                    float4 w = *(const float4*)(qsub + g);
                    v.x -= w.x; v.y -= w.y; v.z -= w.z; v.w -= w.w;
                }
            }
            short8 a0h = *(short8*)&Ah[buf][l15][quad * 8];
            short8 a0l = *(short8*)&Al[buf][l15][quad * 8];
            short8 a1h = *(short8*)&Ah[buf][16 + l15][quad * 8];
            short8 a1l = *(short8*)&Al[buf][16 + l15][quad * 8];
#pragma unroll
            for (int j = 0; j < 4; j++) {
                int tile = ct * 16 + cg * 4 + j;
                size_t off = ((size_t)(tile * 16 + kc) * 64 + lane) * 8;
                short8 bh = *(const short8*)(pkHi + off);
                short8 bl = *(const short8*)(pkLo + off);
                acc[0][j] = __builtin_amdgcn_mfma_f32_16x16x32_bf16(a0h, bh, acc[0][j], 0, 0, 0);
                acc[0][j] = __builtin_amdgcn_mfma_f32_16x16x32_bf16(a0l, bh, acc[0][j], 0, 0, 0);
                acc[0][j] = __builtin_amdgcn_mfma_f32_16x16x32_bf16(a0h, bl, acc[0][j], 0, 0, 0);
                acc[1][j] = __builtin_amdgcn_mfma_f32_16x16x32_bf16(a1h, bh, acc[1][j], 0, 0, 0);
                acc[1][j] = __builtin_amdgcn_mfma_f32_16x16x32_bf16(a1l, bh, acc[1][j], 0, 0, 0);
                acc[1][j] = __builtin_amdgcn_mfma_f32_16x16x32_bf16(a1h, bl, acc[1][j], 0, 0, 0);
            }
            if (pref) {
                ushort4 h, l;
                h.x = f2bf(v.x); l.x = f2bf(v.x - __uint_as_float(((unsigned)h.x) << 16));
                h.y = f2bf(v.y); l.y = f2bf(v.y - __uint_as_float(((unsigned)h.y) << 16));
                h.z = f2bf(v.z); l.z = f2bf(v.z - __uint_as_float(((unsigned)h.z) << 16));
                h.w = f2bf(v.w); l.w = f2bf(v.w - __uint_as_float(((unsigned)h.w) << 16));
                *(ushort4*)&Ah[1 - buf][st_row][st_k4] = h;
                *(ushort4*)&Al[1 - buf][st_row][st_k4] = l;
            }
            __syncthreads();
        }

        // in-lane top-3 update (codes ascending => tie keeps lowest index)
#pragma unroll
        for (int j = 0; j < 4; j++) {
            int code = (ct * 16 + cg * 4 + j) * 16 + l15;
            float nrm = s_nrm[code];
#pragma unroll
            for (int rt = 0; rt < 2; rt++)
#pragma unroll
                for (int reg = 0; reg < 4; reg++) {
                    float v = nrm - 2.0f * acc[rt][j][reg];
                    int s = rt * 4 + reg;
                    bool b1 = v < td1[s];
                    bool b2 = v < td2[s];
                    bool b3 = v < td3[s];
                    td3[s] = b2 ? td2[s] : (b3 ? v : td3[s]);
                    ti2[s] = b1 ? ti1[s] : (b2 ? code : ti2[s]);
                    td2[s] = b1 ? td1[s] : (b2 ? v : td2[s]);
                    ti1[s] = b1 ? code : ti1[s];
                    td1[s] = b1 ? v : td1[s];
                }
        }
    }

    // butterfly merge over 16 l15-lanes (quad preserved)
#pragma unroll
    for (int m = 1; m <= 8; m <<= 1) {
#pragma unroll
        for (int s = 0; s < 8; s++) {
            float o1 = __shfl_xor(td1[s], m); int oi1 = __shfl_xor(ti1[s], m);
            float o2 = __shfl_xor(td2[s], m); int oi2 = __shfl_xor(ti2[s], m);
            float o3 = __shfl_xor(td3[s], m);
            bool aw = (td1[s] < o1) || (td1[s] == o1 && ti1[s] < oi1);
            float w2 = aw ? td2[s] : o2; int wi2 = aw ? ti2[s] : oi2;
            float w3 = aw ? td3[s] : o3;
            float n1 = aw ? td1[s] : o1; int ni1 = aw ? ti1[s] : oi1;
            float p1 = aw ? o1 : td1[s]; int pi1 = aw ? oi1 : ti1[s];
            float p2 = aw ? o2 : td2[s];
            bool sw = (w2 < p1) || (w2 == p1 && wi2 < pi1);
            float n2 = sw ? w2 : p1; int ni2 = sw ? wi2 : pi1;
            float n3 = sw ? fminf(p1, w3) : fminf(w2, p2);
            td1[s] = n1; ti1[s] = ni1; td2[s] = n2; ti2[s] = ni2; td3[s] = n3;
        }
    }

    if (l15 == 0) {
#pragma unroll
        for (int s = 0; s < 8; s++) {
            int row = (s >> 2) * 16 + quad * 4 + (s & 3);
            m_d1[cg][row] = td1[s]; m_i1[cg][row] = ti1[s];
            m_d2[cg][row] = td2[s]; m_i2[cg][row] = ti2[s];
            m_d3[cg][row] = td3[s];
        }
    }
    __syncthreads();

    // 4-way cg merge + flagging (one thread per row)
    if (tid < BR) {
        int r = tid;
        float d1 = m_d1[0][r]; int i1 = m_i1[0][r];
        float d2 = m_d2[0][r]; int i2 = m_i2[0][r];
        float d3 = m_d3[0][r];
#pragma unroll
        for (int c = 1; c < 4; c++) {
            float o1 = m_d1[c][r]; int oi1 = m_i1[c][r];
            float o2 = m_d2[c][r]; int oi2 = m_i2[c][r];
            float o3 = m_d3[c][r];
            bool aw = (d1 < o1) || (d1 == o1 && i1 < oi1);
            float w2 = aw ? d2 : o2; int wi2 = aw ? i2 : oi2;
            float w3 = aw ? d3 : o3;
            float n1 = aw ? d1 : o1; int ni1 = aw ? i1 : oi1;
            float p1 = aw ? o1 : d1; int pi1 = aw ? oi1 : i1;
            float p2 = aw ? o2 : d2;
            bool sw = (w2 < p1) || (w2 == p1 && wi2 < pi1);
            float n2 = sw ? w2 : p1; int ni2 = sw ? wi2 : pi1;
            float n3 = sw ? fminf(p1, w3) : fminf(w2, p2);
            d1 = n1; i1 = ni1; d2 = n2; i2 = ni2; d3 = n3;
        }
        int flag = 0;
        if (d3 - d1 < MARGIN) flag = 2;          // >=3 candidates: full fallback
        else if (d2 - d1 < MARGIN) flag = 1;     // 2 candidates: exact rescore
        s_i1[r] = i1; s_i2[r] = i2; s_flag[r] = flag;
        if (flag == 2) {
            int p = atomicAdd(fbCnt, 1);
            if (p < 32768) fbList[p] = row0 + r;
        }
    }
    __syncthreads();

    // exact fp32 rescore of 2-candidate rows (wave-cooperative)
    for (int r = cg; r < BR; r += 4) {
        if (s_flag[r] != 1) continue;
        int i1 = s_i1[r], i2 = s_i2[r];
        size_t g = (size_t)(row0 + r) * DDIM + lane * 8;
        float rv[8];
        *(float4*)&rv[0] = *(const float4*)(rsrc + g);
        *(float4*)&rv[4] = *(const float4*)(rsrc + g + 4);
        if (qsub) {
            float4 w0 = *(const float4*)(qsub + g);
            float4 w1 = *(const float4*)(qsub + g + 4);
            rv[0] -= w0.x; rv[1] -= w0.y; rv[2] -= w0.z; rv[3] -= w0.w;
            rv[4] -= w1.x; rv[5] -= w1.y; rv[6] -= w1.z; rv[7] -= w1.w;
        }
        float c1[8], c2[8];
        *(float4*)&c1[0] = *(const float4*)(cbq + (size_t)i1 * DDIM + lane * 8);
        *(float4*)&c1[4] = *(const float4*)(cbq + (size_t)i1 * DDIM + lane * 8 + 4);
        *(float4*)&c2[0] = *(const float4*)(cbq + (size_t)i2 * DDIM + lane * 8);
        *(float4*)&c2[4] = *(const float4*)(cbq + (size_t)i2 * DDIM + lane * 8 + 4);
        float e1 = 0.0f, e2 = 0.0f;
#pragma unroll
        for (int i = 0; i < 8; i++) { e1 = fmaf(rv[i], c1[i], e1); e2 = fmaf(rv[i], c2[i], e2); }
#pragma unroll
        for (int m = 32; m >= 1; m >>= 1) { e1 += __shfl_xor(e1, m); e2 += __shfl_xor(e2, m); }
        float dd1 = s_nrm[i1] - 2.0f * e1;
        float dd2 = s_nrm[i2] - 2.0f * e2;
        bool take2 = (dd2 < dd1) || (dd2 == dd1 && i2 < i1);
        if (lane == 0) s_i1[r] = take2 ? i2 : i1;
    }
    __syncthreads();

    if (tid < BR) idx_out[(size_t)(row0 + tid) * QD + q] = (float)s_i1[tid];

    // update phase: resid_new = r - cb[idx]; loss += ||resid_new||^2 (skip fallback rows)
    double ls = 0.0;
#pragma unroll 4
    for (int it = 0; it < 16; it++) {
        int flat = tid + TPB * it;         // 0..4095 float4 chunks
        int row = flat >> 7;
        int c4 = (flat & 127) * 4;
        if (s_flag[row] == 2) continue;
        size_t g = (size_t)(row0 + row) * DDIM + c4;
        float4 r = *(const float4*)(rsrc + g);
        if (qsub) {
            float4 w = *(const float4*)(qsub + g);
            r.x -= w.x; r.y -= w.y; r.z -= w.z; r.w -= w.w;
        }
        float4 cv = *(const float4*)(cbq + (size_t)s_i1[row] * DDIM + c4);
        float4 nr;
        nr.x = r.x - cv.x; nr.y = r.y - cv.y; nr.z = r.z - cv.z; nr.w = r.w - cv.w;
        if (resid) {
            *(float4*)(resid + g) = nr;
        } else {
            float4 qo = *(float4*)(quant + g);
            qo.x += cv.x; qo.y += cv.y; qo.z += cv.z; qo.w += cv.w;
            *(float4*)(quant + g) = qo;
        }
        ls += (double)nr.x * nr.x + (double)nr.y * nr.y +
              (double)nr.z * nr.z + (double)nr.w * nr.w;
    }
#pragma unroll
    for (int m = 32; m >= 1; m >>= 1) ls += __shfl_down(ls, m);
    if ((tid & 63) == 0) s_part[tid >> 6] = ls;
    __syncthreads();
    if (tid == 0) {
        double t = s_part[0] + s_part[1] + s_part[2] + s_part[3];
        atomicAdd(lossq, t);
    }
}

// ---------------------------------------------------------------- full-scan fallback (rare rows)
__global__ __launch_bounds__(256) void vq_fallback(
    const float* __restrict__ rsrc, const float* __restrict__ qsub,
    float* __restrict__ resid, float* __restrict__ quant,
    const float* __restrict__ cbq, const float* __restrict__ normq,
    float* __restrict__ idx_out, double* __restrict__ lossq,
    const int* __restrict__ fbCnt, const int* __restrict__ fbList, int q) {
    __shared__ float r_s[DDIM];
    __shared__ unsigned long long s_best;
    int tid = threadIdx.x;
    int n = *fbCnt; if (n > 32768) n = 32768;
    for (int w = blockIdx.x; w < n; w += gridDim.x) {
        int row = fbList[w];
        if (tid == 0) s_best = ~0ull;
        if (tid < 128) {
            size_t g = (size_t)row * DDIM + tid * 4;
            float4 v = *(const float4*)(rsrc + g);
            if (qsub) {
                float4 x = *(const float4*)(qsub + g);
                v.x -= x.x; v.y -= x.y; v.z -= x.z; v.w -= x.w;
            }
            *(float4*)&r_s[tid * 4] = v;
        }
        __syncthreads();
#pragma unroll
        for (int cc = 0; cc < 4; cc++) {
            int c = tid + 256 * cc;
            float dot = 0.0f;
            for (int k4 = 0; k4 < 128; k4++) {
                float4 cv = *(const float4*)(cbq + (size_t)c * DDIM + k4 * 4);
                float4 rv = *(const float4*)&r_s[k4 * 4];
                dot = fmaf(cv.x, rv.x, dot); dot = fmaf(cv.y, rv.y, dot);
                dot = fmaf(cv.z, rv.z, dot); dot = fmaf(cv.w, rv.w, dot);
            }
            float dist = normq[c] - 2.0f * dot;
            unsigned b = __float_as_uint(dist);
            b = (b & 0x80000000u) ? ~b : (b | 0x80000000u);
            unsigned long long key = (((unsigned long long)b) << 32) | (unsigned)c;
            atomicMin(&s_best, key);
        }
        __syncthreads();
        int idx = (int)(s_best & 0xffffffffull);
        if (tid == 0) idx_out[(size_t)row * QD + q] = (float)idx;
        double ls = 0.0;
        if (tid < 128) {
            size_t g = (size_t)row * DDIM + tid * 4;
            float4 r = *(const float4*)&r_s[tid * 4];
            float4 cv = *(const float4*)(cbq + (size_t)idx * DDIM + tid * 4);
            float4 nr;
            nr.x = r.x - cv.x; nr.y = r.y - cv.y; nr.z = r.z - cv.z; nr.w = r.w - cv.w;
            if (resid) {
                *(float4*)(resid + g) = nr;
            } else {
                float4 qo = *(float4*)(quant + g);
                qo.x += cv.x; qo.y += cv.y; qo.z += cv.z; qo.w += cv.w;
                *(float4*)(quant + g) = qo;
            }
            ls = (double)nr.x * nr.x + (double)nr.y * nr.y +
                 (double)nr.z * nr.z + (double)nr.w * nr.w;
        }
#pragma unroll
        for (int m = 32; m >= 1; m >>= 1) ls += __shfl_down(ls, m);
        if ((tid & 63) == 0 && ls != 0.0) atomicAdd(lossq, ls);
        __syncthreads();
    }
}

// ---------------------------------------------------------------- quant = x - resid_final
__global__ __launch_bounds__(256) void vq_quant_final(const float* __restrict__ x,
                                                      const float* __restrict__ resid,
                                                      float* __restrict__ quant) {
    size_t i = ((size_t)blockIdx.x * 256 + threadIdx.x) * 4;
    float4 xv = *(const float4*)(x + i);
    float4 rv = *(const float4*)(resid + i);
    float4 o;
    o.x = xv.x - rv.x; o.y = xv.y - rv.y; o.z = xv.z - rv.z; o.w = xv.w - rv.w;
    *(float4*)(quant + i) = o;
}

// ---------------------------------------------------------------- finalize losses
__global__ void vq_loss_final(const double* __restrict__ lossws, float* __restrict__ out) {
    int i = threadIdx.x;
    if (i < QD) out[i] = (float)(lossws[i] * (1.0 / (double)((size_t)ROWS * DDIM)));
}

// ---------------------------------------------------------------- launch
extern "C" void kernel_launch(void* const* d_in, const int* in_sizes, int n_in,
                              void* d_out, int out_size, void* d_ws, size_t ws_size,
                              hipStream_t stream) {
    const float* x = (const float*)d_in[0];
    const float* cbs = (const float*)d_in[1];
    float* out = (float*)d_out;
    float* quant = out;
    float* idxo = out + IDX_OFF;
    float* losso = out + LOSS_OFF;

    char* ws = (char*)d_ws;
    double* lossws = (double*)(ws + WS_LOSS);
    int* fbCnt = (int*)(ws + WS_FBCNT);
    int* fbList = (int*)(ws + WS_FBLIST);
    float* norms = (float*)(ws + WS_NORMS);
    ushort* pkHi = (ushort*)(ws + WS_PKHI);
    ushort* pkLo = (ushort*)(ws + WS_PKLO);
    float* resid = (ws_size >= (size_t)WS_RESID + (size_t)QUANT_ELEMS * 4)
                       ? (float*)(ws + WS_RESID) : nullptr;

    hipMemsetAsync(d_ws, 0, 128, stream);
    if (!resid) hipMemsetAsync(d_out, 0, (size_t)out_size * 4, stream);

    vq_norms<<<QD * CDN / 4, 256, 0, stream>>>(cbs, norms);
    vq_cbpack<<<QD * 256, 256, 0, stream>>>(cbs, pkHi, pkLo);   // all levels once

    for (int q = 0; q < QD; q++) {
        const float* cbq = cbs + (size_t)q * CDN * DDIM;
        const float* nq = norms + (size_t)q * CDN;
        const ushort* pH = pkHi + (size_t)q * CDN * DDIM;
        const ushort* pL = pkLo + (size_t)q * CDN * DDIM;
        const float* rsrc;
        const float* qsubA;
        if (resid) {
            rsrc = (q == 0) ? x : resid;
            qsubA = nullptr;
        } else {
            rsrc = x;
            qsubA = quant;
        }
        vq_level_mfma<<<ROWS / BR, TPB, 0, stream>>>(
            rsrc, qsubA, resid, quant, cbq, nq, pH, pL,
            idxo, lossws + q, fbCnt + q, fbList, q);
        vq_fallback<<<128, 256, 0, stream>>>(
            rsrc, qsubA, resid, quant, cbq, nq, idxo, lossws + q,
            fbCnt + q, fbList, q);
    }
    if (resid) {
        vq_quant_final<<<QUANT_ELEMS / 1024, 256, 0, stream>>>(x, resid, quant);
    }
    vq_loss_final<<<1, 64, 0, stream>>>(lossws, losso);
}

// Round 7
// 1791.942 us; speedup vs baseline: 1.1671x; 1.1671x over previous
//
#include <hip/hip_runtime.h>

// Problem constants (fixed by the reference)
#define BD 8
#define SD 4096
#define DDIM 512
#define QD 8
#define CDN 1024
#define ROWS (BD * SD)              // 32768
#define QUANT_ELEMS (ROWS * DDIM)   // 16777216
#define IDX_OFF QUANT_ELEMS
#define LOSS_OFF (QUANT_ELEMS + ROWS * QD)

#define TPB 256
#define BR 32                       // rows per block
// 3-MFMA split (ah*bh + al*bh + ah*bl): max dist error ~2e-3 << MARGIN/2.
#define MARGIN 0.25f

// ws layout (bytes)
#define WS_LOSS 0                   // 8 doubles
#define WS_FBCNT 64                 // 8 ints
#define WS_FBLIST 4096              // 32768 ints (128 KB)
#define WS_NORMS 0x40000            // 32 KB
#define WS_PKHI 0x100000            // 8 MB (all levels)
#define WS_PKLO 0x900000            // 8 MB
#define WS_RESID 0x1100000          // 64 MB

typedef __attribute__((ext_vector_type(8))) short short8;
typedef __attribute__((ext_vector_type(4))) float f32x4;

__device__ __forceinline__ ushort f2bf(float x) {
    unsigned u = __float_as_uint(x);
    u += 0x7fff + ((u >> 16) & 1);          // RTNE
    return (ushort)(u >> 16);
}

// ---------------------------------------------------------------- norms
__global__ __launch_bounds__(256) void vq_norms(const float* __restrict__ cb,
                                                float* __restrict__ norms) {
    int code = blockIdx.x * 4 + (threadIdx.x >> 6);
    int lane = threadIdx.x & 63;
    const float4* p = (const float4*)(cb + (size_t)code * DDIM);
    float4 a = p[lane];
    float4 b = p[lane + 64];
    float s = a.x * a.x + a.y * a.y + a.z * a.z + a.w * a.w +
              b.x * b.x + b.y * b.y + b.z * b.z + b.w * b.w;
#pragma unroll
    for (int m = 32; m >= 1; m >>= 1) s += __shfl_xor(s, m);
    if (lane == 0) norms[code] = s;
}

// ---------------------------------------------------------------- cb pack (ALL levels)
// Frag-major bf16 hi/lo per level: slot s covers code=tile*16+(lane&15),
// k = kc*32 + (lane>>4)*8 + j.  Wave B-load = 64 lanes x 16B contiguous.
__global__ __launch_bounds__(256) void vq_cbpack(const float* __restrict__ cbs,
                                                 ushort* __restrict__ pkHi,
                                                 ushort* __restrict__ pkLo) {
    int sg = blockIdx.x * 256 + threadIdx.x;   // 0..524287 (8 levels x 65536 slots)
    int lvl = sg >> 16;
    int s = sg & 65535;
    int tile = s >> 10;
    int kc = (s >> 6) & 15;
    int ln = s & 63;
    int code = tile * 16 + (ln & 15);
    int k0 = kc * 32 + (ln >> 4) * 8;
    const float* p = cbs + (size_t)lvl * CDN * DDIM + (size_t)code * DDIM + k0;
    float f[8];
    *(float4*)&f[0] = *(const float4*)p;
    *(float4*)&f[4] = *(const float4*)(p + 4);
    ushort h[8], l[8];
#pragma unroll
    for (int i = 0; i < 8; i++) {
        h[i] = f2bf(f[i]);
        float hf = __uint_as_float(((unsigned)h[i]) << 16);
        l[i] = f2bf(f[i] - hf);
    }
    *(short8*)(pkHi + (size_t)sg * 8) = *(short8*)h;
    *(short8*)(pkLo + (size_t)sg * 8) = *(short8*)l;
}

// ---------------------------------------------------------------- fused level (MFMA)
// Full-K A (hi+lo) staged in LDS once (1 barrier); 64-step (ct,kc) MFMA loop is
// BARRIER-FREE with depth-1 ping-pong prefetch of A-frags (LDS) and B-frags (L2).
// A LDS layout: chunk c=k/8 of row r at  r*512 + ((c ^ (r&7))*8) ushorts —
// XOR swizzle gives <=2 lanes per 4-bank span per 16-lane phase (free, m136).
__global__ __launch_bounds__(TPB, 2) void vq_level_mfma(
    const float* __restrict__ rsrc, const float* __restrict__ qsub,
    float* __restrict__ resid, float* __restrict__ quant,
    const float* __restrict__ cbq, const float* __restrict__ normq,
    const ushort* __restrict__ pkHi, const ushort* __restrict__ pkLo,
    float* __restrict__ idx_out, double* __restrict__ lossq,
    int* __restrict__ fbCnt, int* __restrict__ fbList, int q) {
    __shared__ ushort Ah[BR * 512];          // 32 KB
    __shared__ ushort Al[BR * 512];          // 32 KB
    __shared__ float s_nrm[CDN];             // 4 KB
    __shared__ float m_d1[4][BR], m_d2[4][BR], m_d3[4][BR];
    __shared__ int m_i1[4][BR], m_i2[4][BR];
    __shared__ int s_i1[BR], s_i2[BR], s_flag[BR];
    __shared__ double s_part[4];

    int tid = threadIdx.x;
    int lane = tid & 63;
    int l15 = lane & 15;
    int quad = lane >> 4;
    int cg = tid >> 6;      // wave = code group (0..3)
    int row0 = blockIdx.x * BR;

    for (int i = tid; i < CDN; i += TPB) s_nrm[i] = normq[i];

    // ---- stage full-K A: 2048 chunks of 8 floats, 8 per thread
#pragma unroll
    for (int i = 0; i < 8; i++) {
        int flat = tid + TPB * i;       // 0..2047
        int row = flat >> 6;
        int c = flat & 63;
        size_t g = (size_t)(row0 + row) * DDIM + c * 8;
        float f[8];
        *(float4*)&f[0] = *(const float4*)(rsrc + g);
        *(float4*)&f[4] = *(const float4*)(rsrc + g + 4);
        if (qsub) {
            float4 w0 = *(const float4*)(qsub + g);
            float4 w1 = *(const float4*)(qsub + g + 4);
            f[0] -= w0.x; f[1] -= w0.y; f[2] -= w0.z; f[3] -= w0.w;
            f[4] -= w1.x; f[5] -= w1.y; f[6] -= w1.z; f[7] -= w1.w;
        }
        ushort h[8], l[8];
#pragma unroll
        for (int k = 0; k < 8; k++) {
            h[k] = f2bf(f[k]);
            float hf = __uint_as_float(((unsigned)h[k]) << 16);
            l[k] = f2bf(f[k] - hf);
        }
        int dst = row * 512 + ((c ^ (row & 7)) * 8);
        *(short8*)(Ah + dst) = *(short8*)h;
        *(short8*)(Al + dst) = *(short8*)l;
    }
    __syncthreads();
    // -------- no __syncthreads below until after the MFMA loop --------

    // per-lane top-3 per slot (rt*4+reg)
    float td1[8], td2[8], td3[8];
    int ti1[8], ti2[8];
#pragma unroll
    for (int s = 0; s < 8; s++) { td1[s] = 3.4e38f; td2[s] = 3.4e38f; td3[s] = 3.4e38f; ti1[s] = 0; ti2[s] = 0; }

    short8 aR[2][4], bhR[2][4], blR[2][4];
    f32x4 acc[2][4];
    int aswz = l15 & 7;                 // (16+l15)&7 == l15&7

#define LOADB(g, p) { int ct_ = (g) >> 4, kc_ = (g) & 15; \
    int base_ = ct_ * 131072 + cg * 32768 + kc_ * 512 + lane * 8; \
    _Pragma("unroll") for (int j = 0; j < 4; j++) { \
        bhR[p][j] = *(const short8*)(pkHi + base_ + j * 8192); \
        blR[p][j] = *(const short8*)(pkLo + base_ + j * 8192); } }

#define LOADA(g, p) { int c0_ = (((g) & 15) * 4 + quad) ^ aswz; \
    aR[p][0] = *(short8*)(Ah + l15 * 512 + c0_ * 8); \
    aR[p][1] = *(short8*)(Al + l15 * 512 + c0_ * 8); \
    aR[p][2] = *(short8*)(Ah + (16 + l15) * 512 + c0_ * 8); \
    aR[p][3] = *(short8*)(Al + (16 + l15) * 512 + c0_ * 8); }

#define BODY(g, p) { \
    if (((g) & 15) == 0) { \
        _Pragma("unroll") for (int rt = 0; rt < 2; rt++) \
        _Pragma("unroll") for (int j = 0; j < 4; j++) acc[rt][j] = (f32x4)0.0f; } \
    if ((g) < 63) { LOADB((g) + 1, 1 - (p)); LOADA((g) + 1, 1 - (p)); } \
    _Pragma("unroll") for (int j = 0; j < 4; j++) { \
        acc[0][j] = __builtin_amdgcn_mfma_f32_16x16x32_bf16(aR[p][0], bhR[p][j], acc[0][j], 0, 0, 0); \
        acc[0][j] = __builtin_amdgcn_mfma_f32_16x16x32_bf16(aR[p][1], bhR[p][j], acc[0][j], 0, 0, 0); \
        acc[0][j] = __builtin_amdgcn_mfma_f32_16x16x32_bf16(aR[p][0], blR[p][j], acc[0][j], 0, 0, 0); \
        acc[1][j] = __builtin_amdgcn_mfma_f32_16x16x32_bf16(aR[p][2], bhR[p][j], acc[1][j], 0, 0, 0); \
        acc[1][j] = __builtin_amdgcn_mfma_f32_16x16x32_bf16(aR[p][3], bhR[p][j], acc[1][j], 0, 0, 0); \
        acc[1][j] = __builtin_amdgcn_mfma_f32_16x16x32_bf16(aR[p][2], blR[p][j], acc[1][j], 0, 0, 0); } \
    if (((g) & 15) == 15) { int ct_ = (g) >> 4; \
        _Pragma("unroll") for (int j = 0; j < 4; j++) { \
            int code = (ct_ * 16 + cg * 4 + j) * 16 + l15; \
            float nrm = s_nrm[code]; \
            _Pragma("unroll") for (int rt = 0; rt < 2; rt++) \
            _Pragma("unroll") for (int reg = 0; reg < 4; reg++) { \
                float v = nrm - 2.0f * acc[rt][j][reg]; \
                int s = rt * 4 + reg; \
                bool b1 = v < td1[s]; bool b2 = v < td2[s]; bool b3 = v < td3[s]; \
                td3[s] = b2 ? td2[s] : (b3 ? v : td3[s]); \
                ti2[s] = b1 ? ti1[s] : (b2 ? code : ti2[s]); \
                td2[s] = b1 ? td1[s] : (b2 ? v : td2[s]); \
                ti1[s] = b1 ? code : ti1[s]; \
                td1[s] = b1 ? v : td1[s]; } } } }

    LOADB(0, 0); LOADA(0, 0);
    for (int gp = 0; gp < 32; gp++) {
        int g0 = gp * 2;
        BODY(g0, 0);
        BODY(g0 + 1, 1);
    }
#undef LOADB
#undef LOADA
#undef BODY

    // butterfly merge over 16 l15-lanes (quad preserved)
#pragma unroll
    for (int m = 1; m <= 8; m <<= 1) {
#pragma unroll
        for (int s = 0; s < 8; s++) {
            float o1 = __shfl_xor(td1[s], m); int oi1 = __shfl_xor(ti1[s], m);
            float o2 = __shfl_xor(td2[s], m); int oi2 = __shfl_xor(ti2[s], m);
            float o3 = __shfl_xor(td3[s], m);
            bool aw = (td1[s] < o1) || (td1[s] == o1 && ti1[s] < oi1);
            float w2 = aw ? td2[s] : o2; int wi2 = aw ? ti2[s] : oi2;
            float w3 = aw ? td3[s] : o3;
            float n1 = aw ? td1[s] : o1; int ni1 = aw ? ti1[s] : oi1;
            float p1 = aw ? o1 : td1[s]; int pi1 = aw ? oi1 : ti1[s];
            float p2 = aw ? o2 : td2[s];
            bool sw = (w2 < p1) || (w2 == p1 && wi2 < pi1);
            float n2 = sw ? w2 : p1; int ni2 = sw ? wi2 : pi1;
            float n3 = sw ? fminf(p1, w3) : fminf(w2, p2);
            td1[s] = n1; ti1[s] = ni1; td2[s] = n2; ti2[s] = ni2; td3[s] = n3;
        }
    }

    if (l15 == 0) {
#pragma unroll
        for (int s = 0; s < 8; s++) {
            int row = (s >> 2) * 16 + quad * 4 + (s & 3);
            m_d1[cg][row] = td1[s]; m_i1[cg][row] = ti1[s];
            m_d2[cg][row] = td2[s]; m_i2[cg][row] = ti2[s];
            m_d3[cg][row] = td3[s];
        }
    }
    __syncthreads();

    // 4-way cg merge + flagging (one thread per row)
    if (tid < BR) {
        int r = tid;
        float d1 = m_d1[0][r]; int i1 = m_i1[0][r];
        float d2 = m_d2[0][r]; int i2 = m_i2[0][r];
        float d3 = m_d3[0][r];
#pragma unroll
        for (int c = 1; c < 4; c++) {
            float o1 = m_d1[c][r]; int oi1 = m_i1[c][r];
            float o2 = m_d2[c][r]; int oi2 = m_i2[c][r];
            float o3 = m_d3[c][r];
            bool aw = (d1 < o1) || (d1 == o1 && i1 < oi1);
            float w2 = aw ? d2 : o2; int wi2 = aw ? i2 : oi2;
            float w3 = aw ? d3 : o3;
            float n1 = aw ? d1 : o1; int ni1 = aw ? i1 : oi1;
            float p1 = aw ? o1 : d1; int pi1 = aw ? oi1 : i1;
            float p2 = aw ? o2 : d2;
            bool sw = (w2 < p1) || (w2 == p1 && wi2 < pi1);
            float n2 = sw ? w2 : p1; int ni2 = sw ? wi2 : pi1;
            float n3 = sw ? fminf(p1, w3) : fminf(w2, p2);
            d1 = n1; i1 = ni1; d2 = n2; i2 = ni2; d3 = n3;
        }
        int flag = 0;
        if (d3 - d1 < MARGIN) flag = 2;          // >=3 candidates: full fallback
        else if (d2 - d1 < MARGIN) flag = 1;     // 2 candidates: exact rescore
        s_i1[r] = i1; s_i2[r] = i2; s_flag[r] = flag;
        if (flag == 2) {
            int p = atomicAdd(fbCnt, 1);
            if (p < 32768) fbList[p] = row0 + r;
        }
    }
    __syncthreads();

    // exact fp32 rescore of 2-candidate rows (wave-cooperative)
    for (int r = cg; r < BR; r += 4) {
        if (s_flag[r] != 1) continue;
        int i1 = s_i1[r], i2 = s_i2[r];
        size_t g = (size_t)(row0 + r) * DDIM + lane * 8;
        float rv[8];
        *(float4*)&rv[0] = *(const float4*)(rsrc + g);
        *(float4*)&rv[4] = *(const float4*)(rsrc + g + 4);
        if (qsub) {
            float4 w0 = *(const float4*)(qsub + g);
            float4 w1 = *(const float4*)(qsub + g + 4);
            rv[0] -= w0.x; rv[1] -= w0.y; rv[2] -= w0.z; rv[3] -= w0.w;
            rv[4] -= w1.x; rv[5] -= w1.y; rv[6] -= w1.z; rv[7] -= w1.w;
        }
        float c1[8], c2[8];
        *(float4*)&c1[0] = *(const float4*)(cbq + (size_t)i1 * DDIM + lane * 8);
        *(float4*)&c1[4] = *(const float4*)(cbq + (size_t)i1 * DDIM + lane * 8 + 4);
        *(float4*)&c2[0] = *(const float4*)(cbq + (size_t)i2 * DDIM + lane * 8);
        *(float4*)&c2[4] = *(const float4*)(cbq + (size_t)i2 * DDIM + lane * 8 + 4);
        float e1 = 0.0f, e2 = 0.0f;
#pragma unroll
        for (int i = 0; i < 8; i++) { e1 = fmaf(rv[i], c1[i], e1); e2 = fmaf(rv[i], c2[i], e2); }
#pragma unroll
        for (int m = 32; m >= 1; m >>= 1) { e1 += __shfl_xor(e1, m); e2 += __shfl_xor(e2, m); }
        float dd1 = s_nrm[i1] - 2.0f * e1;
        float dd2 = s_nrm[i2] - 2.0f * e2;
        bool take2 = (dd2 < dd1) || (dd2 == dd1 && i2 < i1);
        if (lane == 0) s_i1[r] = take2 ? i2 : i1;
    }
    __syncthreads();

    if (tid < BR) idx_out[(size_t)(row0 + tid) * QD + q] = (float)s_i1[tid];

    // update phase: resid_new = r - cb[idx]; loss += ||resid_new||^2 (skip fallback rows)
    double ls = 0.0;
#pragma unroll 4
    for (int it = 0; it < 16; it++) {
        int flat = tid + TPB * it;         // 0..4095 float4 chunks
        int row = flat >> 7;
        int c4 = (flat & 127) * 4;
        if (s_flag[row] == 2) continue;
        size_t g = (size_t)(row0 + row) * DDIM + c4;
        float4 r = *(const float4*)(rsrc + g);
        if (qsub) {
            float4 w = *(const float4*)(qsub + g);
            r.x -= w.x; r.y -= w.y; r.z -= w.z; r.w -= w.w;
        }
        float4 cv = *(const float4*)(cbq + (size_t)s_i1[row] * DDIM + c4);
        float4 nr;
        nr.x = r.x - cv.x; nr.y = r.y - cv.y; nr.z = r.z - cv.z; nr.w = r.w - cv.w;
        if (resid) {
            *(float4*)(resid + g) = nr;
        } else {
            float4 qo = *(float4*)(quant + g);
            qo.x += cv.x; qo.y += cv.y; qo.z += cv.z; qo.w += cv.w;
            *(float4*)(quant + g) = qo;
        }
        ls += (double)nr.x * nr.x + (double)nr.y * nr.y +
              (double)nr.z * nr.z + (double)nr.w * nr.w;
    }
#pragma unroll
    for (int m = 32; m >= 1; m >>= 1) ls += __shfl_down(ls, m);
    if ((tid & 63) == 0) s_part[tid >> 6] = ls;
    __syncthreads();
    if (tid == 0) {
        double t = s_part[0] + s_part[1] + s_part[2] + s_part[3];
        atomicAdd(lossq, t);
    }
}

// ---------------------------------------------------------------- full-scan fallback (rare rows)
__global__ __launch_bounds__(256) void vq_fallback(
    const float* __restrict__ rsrc, const float* __restrict__ qsub,
    float* __restrict__ resid, float* __restrict__ quant,
    const float* __restrict__ cbq, const float* __restrict__ normq,
    float* __restrict__ idx_out, double* __restrict__ lossq,
    const int* __restrict__ fbCnt, const int* __restrict__ fbList, int q) {
    __shared__ float r_s[DDIM];
    __shared__ unsigned long long s_best;
    int tid = threadIdx.x;
    int n = *fbCnt; if (n > 32768) n = 32768;
    for (int w = blockIdx.x; w < n; w += gridDim.x) {
        int row = fbList[w];
        if (tid == 0) s_best = ~0ull;
        if (tid < 128) {
            size_t g = (size_t)row * DDIM + tid * 4;
            float4 v = *(const float4*)(rsrc + g);
            if (qsub) {
                float4 x = *(const float4*)(qsub + g);
                v.x -= x.x; v.y -= x.y; v.z -= x.z; v.w -= x.w;
            }
            *(float4*)&r_s[tid * 4] = v;
        }
        __syncthreads();
#pragma unroll
        for (int cc = 0; cc < 4; cc++) {
            int c = tid + 256 * cc;
            float dot = 0.0f;
            for (int k4 = 0; k4 < 128; k4++) {
                float4 cv = *(const float4*)(cbq + (size_t)c * DDIM + k4 * 4);
                float4 rv = *(const float4*)&r_s[k4 * 4];
                dot = fmaf(cv.x, rv.x, dot); dot = fmaf(cv.y, rv.y, dot);
                dot = fmaf(cv.z, rv.z, dot); dot = fmaf(cv.w, rv.w, dot);
            }
            float dist = normq[c] - 2.0f * dot;
            unsigned b = __float_as_uint(dist);
            b = (b & 0x80000000u) ? ~b : (b | 0x80000000u);
            unsigned long long key = (((unsigned long long)b) << 32) | (unsigned)c;
            atomicMin(&s_best, key);
        }
        __syncthreads();
        int idx = (int)(s_best & 0xffffffffull);
        if (tid == 0) idx_out[(size_t)row * QD + q] = (float)idx;
        double ls = 0.0;
        if (tid < 128) {
            size_t g = (size_t)row * DDIM + tid * 4;
            float4 r = *(const float4*)&r_s[tid * 4];
            float4 cv = *(const float4*)(cbq + (size_t)idx * DDIM + tid * 4);
            float4 nr;
            nr.x = r.x - cv.x; nr.y = r.y - cv.y; nr.z = r.z - cv.z; nr.w = r.w - cv.w;
            if (resid) {
                *(float4*)(resid + g) = nr;
            } else {
                float4 qo = *(float4*)(quant + g);
                qo.x += cv.x; qo.y += cv.y; qo.z += cv.z; qo.w += cv.w;
                *(float4*)(quant + g) = qo;
            }
            ls = (double)nr.x * nr.x + (double)nr.y * nr.y +
                 (double)nr.z * nr.z + (double)nr.w * nr.w;
        }
#pragma unroll
        for (int m = 32; m >= 1; m >>= 1) ls += __shfl_down(ls, m);
        if ((tid & 63) == 0 && ls != 0.0) atomicAdd(lossq, ls);
        __syncthreads();
    }
}

// ---------------------------------------------------------------- quant = x - resid_final
__global__ __launch_bounds__(256) void vq_quant_final(const float* __restrict__ x,
                                                      const float* __restrict__ resid,
                                                      float* __restrict__ quant) {
    size_t i = ((size_t)blockIdx.x * 256 + threadIdx.x) * 4;
    float4 xv = *(const float4*)(x + i);
    float4 rv = *(const float4*)(resid + i);
    float4 o;
    o.x = xv.x - rv.x; o.y = xv.y - rv.y; o.z = xv.z - rv.z; o.w = xv.w - rv.w;
    *(float4*)(quant + i) = o;
}

// ---------------------------------------------------------------- finalize losses
__global__ void vq_loss_final(const double* __restrict__ lossws, float* __restrict__ out) {
    int i = threadIdx.x;
    if (i < QD) out[i] = (float)(lossws[i] * (1.0 / (double)((size_t)ROWS * DDIM)));
}

// ---------------------------------------------------------------- launch
extern "C" void kernel_launch(void* const* d_in, const int* in_sizes, int n_in,
                              void* d_out, int out_size, void* d_ws, size_t ws_size,
                              hipStream_t stream) {
    const float* x = (const float*)d_in[0];
    const float* cbs = (const float*)d_in[1];
    float* out = (float*)d_out;
    float* quant = out;
    float* idxo = out + IDX_OFF;
    float* losso = out + LOSS_OFF;

    char* ws = (char*)d_ws;
    double* lossws = (double*)(ws + WS_LOSS);
    int* fbCnt = (int*)(ws + WS_FBCNT);
    int* fbList = (int*)(ws + WS_FBLIST);
    float* norms = (float*)(ws + WS_NORMS);
    ushort* pkHi = (ushort*)(ws + WS_PKHI);
    ushort* pkLo = (ushort*)(ws + WS_PKLO);
    float* resid = (ws_size >= (size_t)WS_RESID + (size_t)QUANT_ELEMS * 4)
                       ? (float*)(ws + WS_RESID) : nullptr;

    hipMemsetAsync(d_ws, 0, 128, stream);
    if (!resid) hipMemsetAsync(d_out, 0, (size_t)out_size * 4, stream);

    vq_norms<<<QD * CDN / 4, 256, 0, stream>>>(cbs, norms);
    vq_cbpack<<<QD * 256, 256, 0, stream>>>(cbs, pkHi, pkLo);   // all levels once

    for (int q = 0; q < QD; q++) {
        const float* cbq = cbs + (size_t)q * CDN * DDIM;
        const float* nq = norms + (size_t)q * CDN;
        const ushort* pH = pkHi + (size_t)q * CDN * DDIM;
        const ushort* pL = pkLo + (size_t)q * CDN * DDIM;
        const float* rsrc;
        const float* qsubA;
        if (resid) {
            rsrc = (q == 0) ? x : resid;
            qsubA = nullptr;
        } else {
            rsrc = x;
            qsubA = quant;
        }
        vq_level_mfma<<<ROWS / BR, TPB, 0, stream>>>(
            rsrc, qsubA, resid, quant, cbq, nq, pH, pL,
            idxo, lossws + q, fbCnt + q, fbList, q);
        vq_fallback<<<128, 256, 0, stream>>>(
            rsrc, qsubA, resid, quant, cbq, nq, idxo, lossws + q,
            fbCnt + q, fbList, q);
    }
    if (resid) {
        vq_quant_final<<<QUANT_ELEMS / 1024, 256, 0, stream>>>(x, resid, quant);
    }
    vq_loss_final<<<1, 64, 0, stream>>>(lossws, losso);
}